// Round 19
// baseline (107.341 us; speedup 1.0000x reference)
//
#include <hip/hip_runtime.h>

typedef __attribute__((ext_vector_type(8))) __bf16 bf16x8;
typedef __attribute__((ext_vector_type(4))) __bf16 bf16x4;
typedef __attribute__((ext_vector_type(4))) float f32x4;

#define NB 4
#define SEQ 2048
#define HID 768
#define NH 12
#define HD 64
#define NC 1280   // compact key capacity per batch (5 x 256-tiles; n_b~1024)

#define MFMA(a,b,c) __builtin_amdgcn_mfma_f32_16x16x32_bf16(a, b, c, 0, 0, 0)

// ---------------------------------------------------------------- prep
// Blocks 0..3: per-batch ordered mask compaction (wave 0; ballot + prefix
// popcount, deterministic). Blocks 4..3939: fp32->bf16 convert of X then W.
__global__ __launch_bounds__(256) void prep_kernel(
    const float* __restrict__ mask, const float* __restrict__ X,
    const float* __restrict__ Wq, const float* __restrict__ Wk,
    const float* __restrict__ Wv,
    int* __restrict__ idx, int* __restrict__ counts,
    __bf16* __restrict__ Xb, __bf16* __restrict__ Wb) {
  int blk = blockIdx.x;
  if (blk < NB) {
    int lane = threadIdx.x;
    if (lane < 64) {
      int b = blk;
      int base = 0;
      for (int c = 0; c < SEQ / 64; c++) {
        float mv = mask[b * SEQ + c * 64 + lane];
        unsigned long long ball = __ballot(mv >= 0.0f);
        int pre = __popcll(ball & ((1ull << lane) - 1ull));
        if (mv >= 0.0f) idx[b * SEQ + base + pre] = c * 64 + lane;
        base += (int)__popcll(ball);
      }
      if (lane == 0) counts[b] = base;
    }
    return;
  }
  const long NX = (long)NB * SEQ * HID;   // 6291456
  const long NW = (long)HID * HID;        // 589824
  long i8 = ((long)(blk - NB) * 256 + threadIdx.x) * 8;
  const float* src;
  __bf16* dst;
  if (i8 < NX) {
    src = X + i8; dst = Xb + i8;
  } else {
    long j = i8 - NX;                     // < 1769472
    int w = (int)(j / NW);
    long r = j - (long)w * NW;
    src = (w == 0 ? Wq : (w == 1 ? Wk : Wv)) + r;
    dst = Wb + j;
  }
  const float4* s4 = (const float4*)src;
  float4 a = s4[0], b = s4[1];
  bf16x8 v;
  v[0] = (__bf16)a.x; v[1] = (__bf16)a.y; v[2] = (__bf16)a.z; v[3] = (__bf16)a.w;
  v[4] = (__bf16)b.x; v[5] = (__bf16)b.y; v[6] = (__bf16)b.z; v[7] = (__bf16)b.w;
  *(bf16x8*)dst = v;
}

// ---------------------------------------------------------------- QKV GEMM
// UNCHANGED from r18 (neutral vs r17, kept): 256x256 tile, 8 waves (4m x 2n),
// BK=64, 12 rounds, T14 reg-staged 2-barrier skeleton, grid 216.
// Q from full Xb; K/V gather compacted rows via idx[] on the fly.
// 128B LDS rows + 8-chunk XOR swizzle slot = c ^ (r&7).
// Q pre-scaled by 0.125*log2(e) for log2-domain softmax.
__global__ __launch_bounds__(512) void qkv_kernel(
    const __bf16* __restrict__ Xb, const int* __restrict__ idx,
    const int* __restrict__ counts, const __bf16* __restrict__ Wb,
    const float* __restrict__ bq, const float* __restrict__ bk,
    const float* __restrict__ bv,
    __bf16* __restrict__ Qb, __bf16* __restrict__ Kc,
    __bf16* __restrict__ Vtc) {
  __shared__ alignas(16) __bf16 As[16384];  // [256 rows][64 k]
  __shared__ alignas(16) __bf16 Bs[16384];  // [256 n-rows][64 k]
  int tid = threadIdx.x, lane = tid & 63, wid = tid >> 6;  // wid 0..7
  // grid 216: [0,96) Q (32 m-tiles x 3 n), [96,156) K (20 x 3), [156,216) V
  int bidx = blockIdx.x;
  int w, tm, n0;
  if (bidx < 96)       { w = 0; tm = bidx / 3;          n0 = (bidx % 3) * 256; }
  else if (bidx < 156) { w = 1; tm = (bidx - 96) / 3;   n0 = ((bidx - 96) % 3) * 256; }
  else                 { w = 2; tm = (bidx - 156) / 3;  n0 = ((bidx - 156) % 3) * 256; }
  int m0 = tm * 256;
  int wm = wid >> 1, wn = wid & 1;   // wm 0..3 (m, 64 rows), wn 0..1 (n, 128)
  int la = lane & 15, lg = lane >> 4;

  // staging: r0 = tid>>3 (0..63), cs = tid&7; A/B pass p covers rows p*64+r0.
  int r0 = tid >> 3, csw = (tid & 7) ^ (r0 & 7);
  long aoff[4];
  if (w == 0) {
#pragma unroll
    for (int p = 0; p < 4; p++)
      aoff[p] = (long)(m0 + p * 64 + r0) * HID + csw * 8;
  } else {
    // on-the-fly gather: compact row j -> original row idx[bI][j]
    int bI = m0 / NC, jbase = m0 - bI * NC;   // tiles never cross a batch
    int cnt = counts[bI];
#pragma unroll
    for (int p = 0; p < 4; p++) {
      int j = jbase + p * 64 + r0;
      int src = (j < cnt) ? idx[bI * SEQ + j] : 0;
      aoff[p] = (long)(bI * SEQ + src) * HID + csw * 8;
    }
  }
  long wbase = (long)w * HID * HID;
  long boff[4];
#pragma unroll
  for (int p = 0; p < 4; p++)
    boff[p] = wbase + (long)(n0 + p * 64 + r0) * HID + csw * 8;

  // fragment read offsets (element units): row r, k-chunk kk*4+lg
  int aoffL[2][4], boffL[2][8];
#pragma unroll
  for (int kk = 0; kk < 2; kk++) {
#pragma unroll
    for (int i = 0; i < 4; i++) {
      int r = wm * 64 + i * 16 + la;          // 0..255
      aoffL[kk][i] = r * 64 + (((kk * 4 + lg) ^ (r & 7)) * 8);
    }
#pragma unroll
    for (int j = 0; j < 8; j++) {
      int rb = wn * 128 + j * 16 + la;        // 0..255
      boffL[kk][j] = rb * 64 + (((kk * 4 + lg) ^ (rb & 7)) * 8);
    }
  }

  // prologue: load tile kt=0 into staging registers
  bf16x8 areg[4], breg[4];
#pragma unroll
  for (int p = 0; p < 4; p++) {
    areg[p] = *(const bf16x8*)(Xb + aoff[p]);
    breg[p] = *(const bf16x8*)(Wb + boff[p]);
  }

  f32x4 acc[4][8] = {};
  for (int kt = 0; kt < 12; kt++) {
    // write staged tile kt to LDS (vmcnt wait auto-inserted; loads had the
    // previous compute phase to land). WAR vs tile kt-1 readers: sync2 below.
#pragma unroll
    for (int p = 0; p < 4; p++) {
      *(bf16x8*)(As + p * 4096 + tid * 8) = areg[p];
      *(bf16x8*)(Bs + p * 4096 + tid * 8) = breg[p];
    }
    __syncthreads();  // sync1: tile kt visible to all waves

    // issue loads for tile kt+1 -> in flight under this tile's MFMAs
    // (kt=11 wraps to 0: harmless in-bounds re-load, never written)
    long kn = (kt + 1 == 12) ? 0 : (long)(kt + 1) * 64;
#pragma unroll
    for (int p = 0; p < 4; p++) {
      areg[p] = *(const bf16x8*)(Xb + aoff[p] + kn);
      breg[p] = *(const bf16x8*)(Wb + boff[p] + kn);
    }

#pragma unroll
    for (int kk = 0; kk < 2; kk++) {
      bf16x8 af[4], bfv[8];
#pragma unroll
      for (int i = 0; i < 4; i++) af[i] = *(const bf16x8*)(As + aoffL[kk][i]);
#pragma unroll
      for (int j = 0; j < 8; j++) bfv[j] = *(const bf16x8*)(Bs + boffL[kk][j]);
#pragma unroll
      for (int i = 0; i < 4; i++)
#pragma unroll
        for (int j = 0; j < 8; j++)
          acc[i][j] = MFMA(af[i], bfv[j], acc[i][j]);
    }
    __syncthreads();  // sync2: all waves done reading tile kt
  }

  // epilogue: bias add, bf16 convert.
  // w=0: Qb row-major (pre-scaled); w=1: Kc row-major [5120][768];
  // w=2: Vtc transposed [b][h][d][NC].
  const float* bias = (w == 0) ? bq : ((w == 1) ? bk : bv);
  const float qscale = (w == 0) ? 0.18033688011112042f : 1.0f;  // 0.125*log2e
#pragma unroll
  for (int j = 0; j < 8; j++) {
    int nc = n0 + wn * 128 + j * 16 + la;  // 0..767
    float bb = bias[nc];
#pragma unroll
    for (int i = 0; i < 4; i++) {
      int mrow0 = m0 + wm * 64 + i * 16 + lg * 4;
      f32x4 v = acc[i][j];
      if (w < 2) {
        __bf16* dst = (w == 0 ? Qb : Kc);
#pragma unroll
        for (int reg = 0; reg < 4; reg++)
          dst[(long)(mrow0 + reg) * HID + nc] = (__bf16)((v[reg] + bb) * qscale);
      } else {
        int bI = mrow0 / NC, j0 = mrow0 - bI * NC;  // tiles never cross NC
        int hh = nc >> 6, d = nc & 63;
        bf16x4 pv;
#pragma unroll
        for (int reg = 0; reg < 4; reg++) pv[reg] = (__bf16)(v[reg] + bb);
        *(bf16x4*)(Vtc + ((long)(bI * NH + hh) * HD + d) * NC + j0) = pv;
      }
    }
  }
}

// ---------------------------------------------------------------- attention
// r19: 4 waves x 32 q-rows (2 q-subtiles of 16 per wave), block = 128 q-rows,
// grid unchanged (768 = 3/CU). Each K/V fragment read feeds TWO MFMAs
// (subtiles A,B) -> K/V b128 reads per q-row halve; r18 audit showed attn is
// SIMD issue-port bound (~80%), so fewer instructions per q is the lever.
// Separate PsA/PsB segments per wave (r3 lesson: same-buffer WAR through the
// DS pipe is NOT safe even wave-locally). LDS stays EXACTLY 32768B (r5
// lesson: 48KB allocation collapsed occupancy). Same 2-barrier T14 skeleton,
// same 16x16x32 layouts/swizzles as r14-r18 (proven), fully-valid-tile fast
// path, defer-max THR=8, rowsum via MFMA-ones. Bit-identical math per q-row.
__global__ __launch_bounds__(256) void attn_kernel(
    const __bf16* __restrict__ Qb, const __bf16* __restrict__ Kc,
    const __bf16* __restrict__ Vtc, const int* __restrict__ counts,
    float* __restrict__ out) {
  __shared__ alignas(16) __bf16 Ks[4096];  // [64 keys][64 d]
  __shared__ alignas(16) __bf16 Vs[4096];  // [64 d][64 j]
  __shared__ alignas(16) __bf16 Ps[8192];  // 4 waves x 2 segs x [16 q][64 k]
  int tid = threadIdx.x, lane = tid & 63, wid = tid >> 6;  // wid 0..3
  int qt = blockIdx.x, h = blockIdx.y, b = blockIdx.z;
  int la = lane & 15, lg = lane >> 4;

  int cnt = counts[b];
  int ntiles = (cnt + 63) >> 6;   // >= 1 for this input (n_b ~ 1024)

  // Q fragments for both q-subtiles (A-frag: row = lane&15, k = lg*8+i)
  int qrow = qt * 128 + wid * 32 + la;
  const __bf16* qp = Qb + (long)(b * SEQ + qrow) * HID + h * HD + lg * 8;
  bf16x8 qaA0 = *(const bf16x8*)qp;
  bf16x8 qaA1 = *(const bf16x8*)(qp + 32);
  bf16x8 qaB0 = *(const bf16x8*)(qp + 16L * HID);
  bf16x8 qaB1 = *(const bf16x8*)(qp + 16L * HID + 32);

  // staging maps (source pre-swizzled, LDS dest linear); 256 threads x 16B
  // = 4KB/pass -> 2 passes each for K (rows 0-31, 32-63) and V.
  // (p*32+r0)&7 == r0&7 so the swizzle-inverse chunk is pass-invariant.
  int r0 = tid >> 3, cc = (tid & 7) ^ (r0 & 7);
  long kb0 = (long)(b * NC + r0) * HID + h * HD + cc * 8;
  long kb1 = (long)(b * NC + 32 + r0) * HID + h * HD + cc * 8;
  long vb0 = ((long)(b * NH + h) * HD + r0) * NC + cc * 8;
  long vb1 = ((long)(b * NH + h) * HD + 32 + r0) * NC + cc * 8;

  // fragment read offsets into Ks/Vs (row stride 64 elems = 128B, 8-chunk XOR)
  int koffL[4][2];
#pragma unroll
  for (int j = 0; j < 4; j++) {
    int r = j * 16 + la;
    koffL[j][0] = r * 64 + (((0 + lg) ^ (r & 7)) * 8);
    koffL[j][1] = r * 64 + (((4 + lg) ^ (r & 7)) * 8);
  }
  // per-wave Ps segments: A = wid*2048, B = wid*2048 + 1024 (elements)
  int segA = wid * 2048, segB = segA + 1024;
  int poff0 = la * 64 + (((0 + lg) ^ (la & 7)) * 8);
  int poff1 = la * 64 + (((4 + lg) ^ (la & 7)) * 8);
  // hoisted P-store addresses (loop-invariant; statically indexed)
  int psaddr[4][4];
#pragma unroll
  for (int j = 0; j < 4; j++)
#pragma unroll
    for (int r = 0; r < 4; r++) {
      int row = lg * 4 + r, col = j * 16 + la;
      psaddr[j][r] =
          row * 64 + (((col >> 3) ^ (row & 7)) * 8) + (col & 7);
    }

  float mA[4] = {0.f, 0.f, 0.f, 0.f}, lA[4] = {0.f, 0.f, 0.f, 0.f};
  float mB[4] = {0.f, 0.f, 0.f, 0.f}, lB[4] = {0.f, 0.f, 0.f, 0.f};
  f32x4 accA[4] = {}, accB[4] = {};
  bf16x8 vone;
#pragma unroll
  for (int i = 0; i < 8; i++) vone[i] = (__bf16)1.0f;

  // prologue: load tile 0 into staging registers
  bf16x8 kreg0 = *(const bf16x8*)(Kc + kb0);
  bf16x8 kreg1 = *(const bf16x8*)(Kc + kb1);
  bf16x8 vreg0 = *(const bf16x8*)(Vtc + vb0);
  bf16x8 vreg1 = *(const bf16x8*)(Vtc + vb1);

  for (int t = 0; t < ntiles; t++) {
    // write staged tile t to LDS (vmcnt wait auto-inserted; the loads had
    // the whole previous compute phase to land)
    *(bf16x8*)(Ks + tid * 8) = kreg0;
    *(bf16x8*)(Ks + 2048 + tid * 8) = kreg1;
    *(bf16x8*)(Vs + tid * 8) = vreg0;
    *(bf16x8*)(Vs + 2048 + tid * 8) = vreg1;
    __syncthreads();  // sync1: tile t visible to all waves

    // issue loads for tile t+1 -> in flight under this tile's compute
    // (last iteration wraps to tile 0: harmless in-bounds re-load)
    int tn = (t + 1 == ntiles) ? 0 : (t + 1);
    long ko = (long)tn * (64 * HID);
    kreg0 = *(const bf16x8*)(Kc + kb0 + ko);
    kreg1 = *(const bf16x8*)(Kc + kb1 + ko);
    vreg0 = *(const bf16x8*)(Vtc + vb0 + tn * 64);
    vreg1 = *(const bf16x8*)(Vtc + vb1 + tn * 64);

    // S = Q K^T for both q-subtiles, SHARED K fragments; Q pre-scaled
    f32x4 sA[4], sB[4];
#pragma unroll
    for (int j = 0; j < 4; j++) {
      bf16x8 k0 = *(const bf16x8*)(Ks + koffL[j][0]);
      bf16x8 k1 = *(const bf16x8*)(Ks + koffL[j][1]);
      f32x4 zA = {};
      zA = MFMA(qaA0, k0, zA);
      zA = MFMA(qaA1, k1, zA);
      sA[j] = zA;
      f32x4 zB = {};
      zB = MFMA(qaB0, k0, zB);
      zB = MFMA(qaB1, k1, zB);
      sB[j] = zB;
    }

    // log2-domain arg; per-lane max check (defer-max).
    float mxA[4] = {-1e30f, -1e30f, -1e30f, -1e30f};
    float mxB[4] = {-1e30f, -1e30f, -1e30f, -1e30f};
    if ((t + 1) * 64 <= cnt) {
      // fully-valid tile: no mask compares/selects (mneg = 0 exactly)
#pragma unroll
      for (int j = 0; j < 4; j++)
#pragma unroll
        for (int r = 0; r < 4; r++) {
          float aA = sA[j][r] - mA[r];
          sA[j][r] = aA;
          mxA[r] = fmaxf(mxA[r], aA);
          float aB = sB[j][r] - mB[r];
          sB[j][r] = aB;
          mxB[r] = fmaxf(mxB[r], aB);
        }
    } else {
#pragma unroll
      for (int j = 0; j < 4; j++) {
        float mneg = ((t * 64 + j * 16 + la) < cnt) ? 0.0f : -30000.0f;
#pragma unroll
        for (int r = 0; r < 4; r++) {
          float aA = sA[j][r] + (mneg - mA[r]);
          sA[j][r] = aA;
          mxA[r] = fmaxf(mxA[r], aA);
          float aB = sB[j][r] + (mneg - mB[r]);
          sB[j][r] = aB;
          mxB[r] = fmaxf(mxB[r], aB);
        }
      }
    }
    int ok = 1;
#pragma unroll
    for (int r = 0; r < 4; r++) ok &= (mxA[r] <= 8.f) & (mxB[r] <= 8.f);
    if (__builtin_expect(!__all(ok), 0)) {
      // rare: true row-max reduce + rescale (both q-subtiles)
#pragma unroll
      for (int r = 0; r < 4; r++) {
        float rmA = mxA[r], rmB = mxB[r];
#pragma unroll
        for (int o = 1; o < 16; o <<= 1) {
          rmA = fmaxf(rmA, __shfl_xor(rmA, o, 16));
          rmB = fmaxf(rmB, __shfl_xor(rmB, o, 16));
        }
        rmA = fmaxf(rmA, 0.0f);
        rmB = fmaxf(rmB, 0.0f);
        float cA = __builtin_amdgcn_exp2f(-rmA);
        float cB = __builtin_amdgcn_exp2f(-rmB);
        mA[r] += rmA; lA[r] *= cA;
        mB[r] += rmB; lB[r] *= cB;
#pragma unroll
        for (int jo = 0; jo < 4; jo++) { accA[jo][r] *= cA; accB[jo][r] *= cB; }
#pragma unroll
        for (int j = 0; j < 4; j++) { sA[j][r] -= rmA; sB[j][r] -= rmB; }
      }
    }

    // q-subtile A: P = exp2 -> PsA (swizzled) -> A-frags; rowsum via ones
#pragma unroll
    for (int j = 0; j < 4; j++)
#pragma unroll
      for (int r = 0; r < 4; r++)
        Ps[segA + psaddr[j][r]] = (__bf16)__builtin_amdgcn_exp2f(sA[j][r]);
    bf16x8 paA0 = *(const bf16x8*)(Ps + segA + poff0);
    bf16x8 paA1 = *(const bf16x8*)(Ps + segA + poff1);
    f32x4 zsA = {};
    zsA = MFMA(paA0, vone, zsA);
    zsA = MFMA(paA1, vone, zsA);
#pragma unroll
    for (int r = 0; r < 4; r++) lA[r] += zsA[r];

    // q-subtile B into its own segment (no WAR with A's reads — r3 lesson)
#pragma unroll
    for (int j = 0; j < 4; j++)
#pragma unroll
      for (int r = 0; r < 4; r++)
        Ps[segB + psaddr[j][r]] = (__bf16)__builtin_amdgcn_exp2f(sB[j][r]);
    bf16x8 paB0 = *(const bf16x8*)(Ps + segB + poff0);
    bf16x8 paB1 = *(const bf16x8*)(Ps + segB + poff1);
    f32x4 zsB = {};
    zsB = MFMA(paB0, vone, zsB);
    zsB = MFMA(paB1, vone, zsB);
#pragma unroll
    for (int r = 0; r < 4; r++) lB[r] += zsB[r];

    // O += P V for both q-subtiles, SHARED V fragments
#pragma unroll
    for (int jo = 0; jo < 4; jo++) {
      bf16x8 v0 = *(const bf16x8*)(Vs + koffL[jo][0]);
      bf16x8 v1 = *(const bf16x8*)(Vs + koffL[jo][1]);
      accA[jo] = MFMA(paA0, v0, accA[jo]);
      accA[jo] = MFMA(paA1, v1, accA[jo]);
      accB[jo] = MFMA(paB0, v0, accB[jo]);
      accB[jo] = MFMA(paB1, v1, accB[jo]);
    }

    __syncthreads();  // sync2: all waves done reading tile t
  }

  // epilogue: out[b, s, h*64+d] = acc / l  (both q-subtiles)
#pragma unroll
  for (int jo = 0; jo < 4; jo++)
#pragma unroll
    for (int r = 0; r < 4; r++) {
      int rowA = qt * 128 + wid * 32 + lg * 4 + r;
      int d = jo * 16 + la;
      out[(long)(b * SEQ + rowA) * HID + h * HD + d] = accA[jo][r] / lA[r];
      out[(long)(b * SEQ + rowA + 16) * HID + h * HD + d] = accB[jo][r] / lB[r];
    }
}

// ---------------------------------------------------------------- launch
extern "C" void kernel_launch(void* const* d_in, const int* in_sizes, int n_in,
                              void* d_out, int out_size, void* d_ws, size_t ws_size,
                              hipStream_t stream) {
  const float* X    = (const float*)d_in[0];
  const float* mask = (const float*)d_in[1];
  const float* Wq   = (const float*)d_in[2];
  const float* bq   = (const float*)d_in[3];
  const float* Wk   = (const float*)d_in[4];
  const float* bk   = (const float*)d_in[5];
  const float* Wv   = (const float*)d_in[6];
  const float* bv   = (const float*)d_in[7];

  __bf16* Xb  = (__bf16*)d_ws;           // 6291456
  __bf16* Wb  = Xb + 6291456;            // 1769472 (Wq,Wk,Wv)
  __bf16* Qb  = Wb + 1769472;            // 6291456
  __bf16* Kc  = Qb + 6291456;            // 3932160
  __bf16* Vtc = Kc + 3932160;            // 3932160, layout [b][h][d][NC]
  int* idx    = (int*)(Vtc + 3932160);   // 4*2048 ints
  int* counts = idx + NB * SEQ;          // 4 ints
  float* out  = (float*)d_out;

  prep_kernel<<<dim3(3940), dim3(256), 0, stream>>>(mask, X, Wq, Wk, Wv,
                                                    idx, counts, Xb, Wb);
  qkv_kernel<<<dim3(216), dim3(512), 0, stream>>>(Xb, idx, counts, Wb,
                                                  bq, bk, bv, Qb, Kc, Vtc);
  attn_kernel<<<dim3(16, 12, 4), dim3(256), 0, stream>>>(Qb, Kc, Vtc, counts,
                                                         out);
}

// Round 20
// 98.195 us; speedup vs baseline: 1.0931x; 1.0931x over previous
//
#include <hip/hip_runtime.h>

typedef __attribute__((ext_vector_type(8))) __bf16 bf16x8;
typedef __attribute__((ext_vector_type(4))) __bf16 bf16x4;
typedef __attribute__((ext_vector_type(4))) float f32x4;

#define NB 4
#define SEQ 2048
#define HID 768
#define NH 12
#define HD 64
#define NC 1280   // compact key capacity per batch (5 x 256-tiles; n_b~1024)

#define MFMA(a,b,c) __builtin_amdgcn_mfma_f32_16x16x32_bf16(a, b, c, 0, 0, 0)

// ---------------------------------------------------------------- prep
// Blocks 0..3: per-batch ordered mask compaction (wave 0; ballot + prefix
// popcount, deterministic). Blocks 4..3939: fp32->bf16 convert of X then W.
__global__ __launch_bounds__(256) void prep_kernel(
    const float* __restrict__ mask, const float* __restrict__ X,
    const float* __restrict__ Wq, const float* __restrict__ Wk,
    const float* __restrict__ Wv,
    int* __restrict__ idx, int* __restrict__ counts,
    __bf16* __restrict__ Xb, __bf16* __restrict__ Wb) {
  int blk = blockIdx.x;
  if (blk < NB) {
    int lane = threadIdx.x;
    if (lane < 64) {
      int b = blk;
      int base = 0;
      for (int c = 0; c < SEQ / 64; c++) {
        float mv = mask[b * SEQ + c * 64 + lane];
        unsigned long long ball = __ballot(mv >= 0.0f);
        int pre = __popcll(ball & ((1ull << lane) - 1ull));
        if (mv >= 0.0f) idx[b * SEQ + base + pre] = c * 64 + lane;
        base += (int)__popcll(ball);
      }
      if (lane == 0) counts[b] = base;
    }
    return;
  }
  const long NX = (long)NB * SEQ * HID;   // 6291456
  const long NW = (long)HID * HID;        // 589824
  long i8 = ((long)(blk - NB) * 256 + threadIdx.x) * 8;
  const float* src;
  __bf16* dst;
  if (i8 < NX) {
    src = X + i8; dst = Xb + i8;
  } else {
    long j = i8 - NX;                     // < 1769472
    int w = (int)(j / NW);
    long r = j - (long)w * NW;
    src = (w == 0 ? Wq : (w == 1 ? Wk : Wv)) + r;
    dst = Wb + j;
  }
  const float4* s4 = (const float4*)src;
  float4 a = s4[0], b = s4[1];
  bf16x8 v;
  v[0] = (__bf16)a.x; v[1] = (__bf16)a.y; v[2] = (__bf16)a.z; v[3] = (__bf16)a.w;
  v[4] = (__bf16)b.x; v[5] = (__bf16)b.y; v[6] = (__bf16)b.z; v[7] = (__bf16)b.w;
  *(bf16x8*)dst = v;
}

// ---------------------------------------------------------------- QKV GEMM
// r17 config (best measured): 256x128 tile, 8 waves (4m x 2n), BK=64,
// 12 rounds, T14 reg-staged 2-barrier skeleton, grid 432, bf16 Xb.
// Q from full Xb; K/V gather compacted rows via idx[] on the fly.
// 128B LDS rows + 8-chunk XOR swizzle slot = c ^ (r&7).
// Q pre-scaled by 0.125*log2(e) for log2-domain softmax.
__global__ __launch_bounds__(512) void qkv_kernel(
    const __bf16* __restrict__ Xb, const int* __restrict__ idx,
    const int* __restrict__ counts, const __bf16* __restrict__ Wb,
    const float* __restrict__ bq, const float* __restrict__ bk,
    const float* __restrict__ bv,
    __bf16* __restrict__ Qb, __bf16* __restrict__ Kc,
    __bf16* __restrict__ Vtc) {
  __shared__ alignas(16) __bf16 As[16384];  // [256 rows][64 k]
  __shared__ alignas(16) __bf16 Bs[8192];   // [128 n-rows][64 k]
  int tid = threadIdx.x, lane = tid & 63, wid = tid >> 6;  // wid 0..7
  // grid 432: [0,192) Q (32 m-tiles x 6 n), [192,312) K (20 x 6), [312,432) V
  int bidx = blockIdx.x;
  int w, tm, n0;
  if (bidx < 192)      { w = 0; tm = bidx / 6;          n0 = (bidx % 6) * 128; }
  else if (bidx < 312) { w = 1; tm = (bidx - 192) / 6;  n0 = ((bidx - 192) % 6) * 128; }
  else                 { w = 2; tm = (bidx - 312) / 6;  n0 = ((bidx - 312) % 6) * 128; }
  int m0 = tm * 256;
  int wm = wid >> 1, wn = wid & 1;   // wm 0..3 (m), wn 0..1 (n)
  int la = lane & 15, lg = lane >> 4;

  // staging: r0 = tid>>3 (0..63), cs = tid&7; A pass p covers rows p*64+r0
  // (p=0..3), B pass p covers rows p*64+r0 (p=0..1).
  int r0 = tid >> 3, csw = (tid & 7) ^ (r0 & 7);
  long aoff[4];
  if (w == 0) {
#pragma unroll
    for (int p = 0; p < 4; p++)
      aoff[p] = (long)(m0 + p * 64 + r0) * HID + csw * 8;
  } else {
    // on-the-fly gather: compact row j -> original row idx[bI][j]
    int bI = m0 / NC, jbase = m0 - bI * NC;   // tiles never cross a batch
    int cnt = counts[bI];
#pragma unroll
    for (int p = 0; p < 4; p++) {
      int j = jbase + p * 64 + r0;
      int src = (j < cnt) ? idx[bI * SEQ + j] : 0;
      aoff[p] = (long)(bI * SEQ + src) * HID + csw * 8;
    }
  }
  long wbase = (long)w * HID * HID;
  long boff[2];
#pragma unroll
  for (int p = 0; p < 2; p++)
    boff[p] = wbase + (long)(n0 + p * 64 + r0) * HID + csw * 8;

  // fragment read offsets (element units): row r, k-chunk kk*4+lg
  int aoffL[2][4], boffL[2][4];
#pragma unroll
  for (int kk = 0; kk < 2; kk++)
#pragma unroll
    for (int i = 0; i < 4; i++) {
      int r = wm * 64 + i * 16 + la;          // 0..255
      aoffL[kk][i] = r * 64 + (((kk * 4 + lg) ^ (r & 7)) * 8);
      int rb = wn * 64 + i * 16 + la;         // 0..127
      boffL[kk][i] = rb * 64 + (((kk * 4 + lg) ^ (rb & 7)) * 8);
    }

  // prologue: load tile kt=0 into staging registers
  bf16x8 areg[4], breg[2];
#pragma unroll
  for (int p = 0; p < 4; p++) areg[p] = *(const bf16x8*)(Xb + aoff[p]);
#pragma unroll
  for (int p = 0; p < 2; p++) breg[p] = *(const bf16x8*)(Wb + boff[p]);

  f32x4 acc[4][4] = {};
  for (int kt = 0; kt < 12; kt++) {
    // write staged tile kt to LDS (vmcnt wait auto-inserted; loads had the
    // previous compute phase to land). WAR vs tile kt-1 readers: sync2 below.
#pragma unroll
    for (int p = 0; p < 4; p++)
      *(bf16x8*)(As + p * 4096 + tid * 8) = areg[p];
#pragma unroll
    for (int p = 0; p < 2; p++)
      *(bf16x8*)(Bs + p * 4096 + tid * 8) = breg[p];
    __syncthreads();  // sync1: tile kt visible to all waves

    // issue loads for tile kt+1 -> in flight under this tile's MFMAs
    // (kt=11 wraps to 0: harmless in-bounds re-load, never written)
    long kn = (kt + 1 == 12) ? 0 : (long)(kt + 1) * 64;
#pragma unroll
    for (int p = 0; p < 4; p++) areg[p] = *(const bf16x8*)(Xb + aoff[p] + kn);
#pragma unroll
    for (int p = 0; p < 2; p++) breg[p] = *(const bf16x8*)(Wb + boff[p] + kn);

#pragma unroll
    for (int kk = 0; kk < 2; kk++) {
      bf16x8 af[4], bfv[4];
#pragma unroll
      for (int i = 0; i < 4; i++) af[i] = *(const bf16x8*)(As + aoffL[kk][i]);
#pragma unroll
      for (int j = 0; j < 4; j++) bfv[j] = *(const bf16x8*)(Bs + boffL[kk][j]);
#pragma unroll
      for (int i = 0; i < 4; i++)
#pragma unroll
        for (int j = 0; j < 4; j++)
          acc[i][j] = MFMA(af[i], bfv[j], acc[i][j]);
    }
    __syncthreads();  // sync2: all waves done reading tile kt
  }

  // epilogue: bias add, bf16 convert.
  // w=0: Qb row-major (pre-scaled); w=1: Kc row-major [5120][768];
  // w=2: Vtc transposed [b][h][d][NC].
  const float* bias = (w == 0) ? bq : ((w == 1) ? bk : bv);
  const float qscale = (w == 0) ? 0.18033688011112042f : 1.0f;  // 0.125*log2e
#pragma unroll
  for (int j = 0; j < 4; j++) {
    int nc = n0 + wn * 64 + j * 16 + la;  // 0..767
    float bb = bias[nc];
#pragma unroll
    for (int i = 0; i < 4; i++) {
      int mrow0 = m0 + wm * 64 + i * 16 + lg * 4;
      f32x4 v = acc[i][j];
      if (w < 2) {
        __bf16* dst = (w == 0 ? Qb : Kc);
#pragma unroll
        for (int reg = 0; reg < 4; reg++)
          dst[(long)(mrow0 + reg) * HID + nc] = (__bf16)((v[reg] + bb) * qscale);
      } else {
        int bI = mrow0 / NC, j0 = mrow0 - bI * NC;  // tiles never cross NC
        int hh = nc >> 6, d = nc & 63;
        bf16x4 pv;
#pragma unroll
        for (int reg = 0; reg < 4; reg++) pv[reg] = (__bf16)(v[reg] + bb);
        *(bf16x4*)(Vtc + ((long)(bI * NH + hh) * HD + d) * NC + j0) = pv;
      }
    }
  }
}

// ---------------------------------------------------------------- attention
// r17 config (best measured: 52.2us): r14 single-buffer 2-barrier form +
// fully-valid-tile fast path. 8 waves/block = 128 q-rows (r19 lesson: this
// structure needs >=6 waves/SIMD; trading TLP for issue-count regresses).
// Compacted keys: ntiles=ceil(cnt/64); padded keys -> p = 0 exactly. T14
// async-STAGE split. Flash, log2-domain (Q pre-scaled), defer-max THR=8,
// rowsum via MFMA-ones. 128B LDS rows + 8-chunk XOR swizzle. 32KB LDS.
__global__ __launch_bounds__(512) void attn_kernel(
    const __bf16* __restrict__ Qb, const __bf16* __restrict__ Kc,
    const __bf16* __restrict__ Vtc, const int* __restrict__ counts,
    float* __restrict__ out) {
  __shared__ alignas(16) __bf16 Ks[4096];  // [64 keys][64 d]
  __shared__ alignas(16) __bf16 Vs[4096];  // [64 d][64 j]
  __shared__ alignas(16) __bf16 Ps[8192];  // 8 waves x [16 q][64 k]
  int tid = threadIdx.x, lane = tid & 63, wid = tid >> 6;  // wid 0..7
  int qt = blockIdx.x, h = blockIdx.y, b = blockIdx.z;
  int la = lane & 15, lg = lane >> 4;

  int cnt = counts[b];
  int ntiles = (cnt + 63) >> 6;   // >= 1 for this input (n_b ~ 1024)

  // Q fragments in registers (A-frag: row = lane&15, k = (lane>>4)*8+i)
  int qrow = qt * 128 + wid * 16 + la;
  const __bf16* qp = Qb + (long)(b * SEQ + qrow) * HID + h * HD + lg * 8;
  bf16x8 qa0 = *(const bf16x8*)qp;
  bf16x8 qa1 = *(const bf16x8*)(qp + 32);

  // staging maps (source pre-swizzled, LDS dest linear); 512 threads cover a
  // full 64x64 tile, 16B each. r0 = row (0..63), chunk = c ^ (r&7).
  int r0 = tid >> 3, cc = (tid & 7) ^ (r0 & 7);
  long kbase = (long)(b * NC + r0) * HID + h * HD + cc * 8;     // key rows
  long vbase = ((long)(b * NH + h) * HD + r0) * NC + cc * 8;    // d rows

  // fragment read offsets into Ks/Vs (row stride 64 elems = 128B, 8-chunk XOR)
  int koffL[4][2];
#pragma unroll
  for (int j = 0; j < 4; j++) {
    int r = j * 16 + la;
    koffL[j][0] = r * 64 + (((0 + lg) ^ (r & 7)) * 8);
    koffL[j][1] = r * 64 + (((4 + lg) ^ (r & 7)) * 8);
  }
  int poff0 = wid * 1024 + la * 64 + (((0 + lg) ^ (la & 7)) * 8);
  int poff1 = wid * 1024 + la * 64 + (((4 + lg) ^ (la & 7)) * 8);
  // hoisted P-store addresses (loop-invariant; statically indexed)
  int psaddr[4][4];
#pragma unroll
  for (int j = 0; j < 4; j++)
#pragma unroll
    for (int r = 0; r < 4; r++) {
      int row = lg * 4 + r, col = j * 16 + la;
      psaddr[j][r] =
          wid * 1024 + row * 64 + (((col >> 3) ^ (row & 7)) * 8) + (col & 7);
    }

  float m_run[4] = {0.f, 0.f, 0.f, 0.f}; // log2-domain running max (defer)
  float l_run[4] = {0.f, 0.f, 0.f, 0.f};
  f32x4 acc[4] = {};
  bf16x8 vone;
#pragma unroll
  for (int i = 0; i < 8; i++) vone[i] = (__bf16)1.0f;

  // prologue: load tile 0 into staging registers
  bf16x8 kreg = *(const bf16x8*)(Kc + kbase);
  bf16x8 vreg = *(const bf16x8*)(Vtc + vbase);

  for (int t = 0; t < ntiles; t++) {
    // write staged tile t to LDS (compiler inserts the vmcnt wait here;
    // the loads had the whole previous compute phase to land)
    *(bf16x8*)(Ks + tid * 8) = kreg;
    *(bf16x8*)(Vs + tid * 8) = vreg;
    __syncthreads();  // sync1: tile t visible to all waves

    // issue loads for tile t+1 -> in flight under this tile's compute
    // (last iteration wraps to tile 0: harmless in-bounds re-load)
    int tn = (t + 1 == ntiles) ? 0 : (t + 1);
    kreg = *(const bf16x8*)(Kc + kbase + (long)tn * (64 * HID));
    vreg = *(const bf16x8*)(Vtc + vbase + tn * 64);

    // S = Q K^T  (D: lane holds rows lg*4+r, col = j*16+la); Q pre-scaled
    f32x4 s[4];
#pragma unroll
    for (int j = 0; j < 4; j++) {
      bf16x8 k0 = *(const bf16x8*)(Ks + koffL[j][0]);
      bf16x8 k1 = *(const bf16x8*)(Ks + koffL[j][1]);
      f32x4 z = {};
      z = MFMA(qa0, k0, z);
      z = MFMA(qa1, k1, z);
      s[j] = z;
    }

    // log2-domain arg; per-lane max check (defer-max).
    float mx[4] = {-1e30f, -1e30f, -1e30f, -1e30f};
    if ((t + 1) * 64 <= cnt) {
      // fully-valid tile (16 of ~17): no mask compares/selects at all;
      // identical arithmetic to masked path with mneg = 0.
#pragma unroll
      for (int j = 0; j < 4; j++)
#pragma unroll
        for (int r = 0; r < 4; r++) {
          float a = s[j][r] - m_run[r];
          s[j][r] = a;
          mx[r] = fmaxf(mx[r], a);
        }
    } else {
#pragma unroll
      for (int j = 0; j < 4; j++) {
        float mneg = ((t * 64 + j * 16 + la) < cnt) ? 0.0f : -30000.0f;
#pragma unroll
        for (int r = 0; r < 4; r++) {
          float a = s[j][r] + (mneg - m_run[r]);
          s[j][r] = a;
          mx[r] = fmaxf(mx[r], a);
        }
      }
    }
    int ok = (mx[0] <= 8.f) & (mx[1] <= 8.f) & (mx[2] <= 8.f) & (mx[3] <= 8.f);
    if (__builtin_expect(!__all(ok), 0)) {
      // rare: true row-max reduce + rescale
#pragma unroll
      for (int r = 0; r < 4; r++) {
        float rm = mx[r];
#pragma unroll
        for (int o = 1; o < 16; o <<= 1) rm = fmaxf(rm, __shfl_xor(rm, o, 16));
        rm = fmaxf(rm, 0.0f);
        float corr = __builtin_amdgcn_exp2f(-rm);
        m_run[r] += rm;
        l_run[r] *= corr;
#pragma unroll
        for (int jo = 0; jo < 4; jo++) acc[jo][r] *= corr;
#pragma unroll
        for (int j = 0; j < 4; j++) s[j][r] -= rm;
      }
    }

    // P = exp2(arg) -> bf16 -> per-wave LDS (swizzled) transpose to A-frag
#pragma unroll
    for (int j = 0; j < 4; j++)
#pragma unroll
      for (int r = 0; r < 4; r++)
        Ps[psaddr[j][r]] = (__bf16)__builtin_amdgcn_exp2f(s[j][r]);
    bf16x8 pa0 = *(const bf16x8*)(Ps + poff0);
    bf16x8 pa1 = *(const bf16x8*)(Ps + poff1);

    // l += rowsum(P) via MFMA with ones-B (D layout matches l_run slots)
    f32x4 z = {};
    z = MFMA(pa0, vone, z);
    z = MFMA(pa1, vone, z);
#pragma unroll
    for (int r = 0; r < 4; r++) l_run[r] += z[r];

    // O += P V   (B-frag from Vs rows: row(d) = jo*16+la, k along j)
#pragma unroll
    for (int jo = 0; jo < 4; jo++) {
      bf16x8 v0 = *(const bf16x8*)(Vs + koffL[jo][0]);
      bf16x8 v1 = *(const bf16x8*)(Vs + koffL[jo][1]);
      acc[jo] = MFMA(pa0, v0, acc[jo]);
      acc[jo] = MFMA(pa1, v1, acc[jo]);
    }

    __syncthreads();  // sync2: all waves done reading tile t
  }

  // epilogue: out[b, s, h*64+d] = acc / l
#pragma unroll
  for (int jo = 0; jo < 4; jo++)
#pragma unroll
    for (int r = 0; r < 4; r++) {
      int row = qt * 128 + wid * 16 + lg * 4 + r;
      int d = jo * 16 + la;
      out[(long)(b * SEQ + row) * HID + h * HD + d] = acc[jo][r] / l_run[r];
    }
}

// ---------------------------------------------------------------- launch
extern "C" void kernel_launch(void* const* d_in, const int* in_sizes, int n_in,
                              void* d_out, int out_size, void* d_ws, size_t ws_size,
                              hipStream_t stream) {
  const float* X    = (const float*)d_in[0];
  const float* mask = (const float*)d_in[1];
  const float* Wq   = (const float*)d_in[2];
  const float* bq   = (const float*)d_in[3];
  const float* Wk   = (const float*)d_in[4];
  const float* bk   = (const float*)d_in[5];
  const float* Wv   = (const float*)d_in[6];
  const float* bv   = (const float*)d_in[7];

  __bf16* Xb  = (__bf16*)d_ws;           // 6291456
  __bf16* Wb  = Xb + 6291456;            // 1769472 (Wq,Wk,Wv)
  __bf16* Qb  = Wb + 1769472;            // 6291456
  __bf16* Kc  = Qb + 6291456;            // 3932160
  __bf16* Vtc = Kc + 3932160;            // 3932160, layout [b][h][d][NC]
  int* idx    = (int*)(Vtc + 3932160);   // 4*2048 ints
  int* counts = idx + NB * SEQ;          // 4 ints
  float* out  = (float*)d_out;

  prep_kernel<<<dim3(3940), dim3(256), 0, stream>>>(mask, X, Wq, Wk, Wv,
                                                    idx, counts, Xb, Wb);
  qkv_kernel<<<dim3(432), dim3(512), 0, stream>>>(Xb, idx, counts, Wb,
                                                  bq, bk, bv, Qb, Kc, Vtc);
  attn_kernel<<<dim3(16, 12, 4), dim3(512), 0, stream>>>(Qb, Kc, Vtc, counts,
                                                         out);
}

// Round 21
// 92.246 us; speedup vs baseline: 1.1636x; 1.0645x over previous
//
#include <hip/hip_runtime.h>

typedef __attribute__((ext_vector_type(8))) __bf16 bf16x8;
typedef __attribute__((ext_vector_type(4))) __bf16 bf16x4;
typedef __attribute__((ext_vector_type(4))) float f32x4;

#define NB 4
#define SEQ 2048
#define HID 768
#define NH 12
#define HD 64
#define NC 1280   // compact key capacity per batch (5 x 256-tiles; n_b~1024)

#define MFMA(a,b,c) __builtin_amdgcn_mfma_f32_16x16x32_bf16(a, b, c, 0, 0, 0)

// ---------------------------------------------------------------- prep
// Blocks 0..3: per-batch ordered mask compaction (wave 0; ballot + prefix
// popcount, deterministic). Blocks 4..3939: fp32->bf16 convert of X then W.
__global__ __launch_bounds__(256) void prep_kernel(
    const float* __restrict__ mask, const float* __restrict__ X,
    const float* __restrict__ Wq, const float* __restrict__ Wk,
    const float* __restrict__ Wv,
    int* __restrict__ idx, int* __restrict__ counts,
    __bf16* __restrict__ Xb, __bf16* __restrict__ Wb) {
  int blk = blockIdx.x;
  if (blk < NB) {
    int lane = threadIdx.x;
    if (lane < 64) {
      int b = blk;
      int base = 0;
      for (int c = 0; c < SEQ / 64; c++) {
        float mv = mask[b * SEQ + c * 64 + lane];
        unsigned long long ball = __ballot(mv >= 0.0f);
        int pre = __popcll(ball & ((1ull << lane) - 1ull));
        if (mv >= 0.0f) idx[b * SEQ + base + pre] = c * 64 + lane;
        base += (int)__popcll(ball);
      }
      if (lane == 0) counts[b] = base;
    }
    return;
  }
  const long NX = (long)NB * SEQ * HID;   // 6291456
  const long NW = (long)HID * HID;        // 589824
  long i8 = ((long)(blk - NB) * 256 + threadIdx.x) * 8;
  const float* src;
  __bf16* dst;
  if (i8 < NX) {
    src = X + i8; dst = Xb + i8;
  } else {
    long j = i8 - NX;                     // < 1769472
    int w = (int)(j / NW);
    long r = j - (long)w * NW;
    src = (w == 0 ? Wq : (w == 1 ? Wk : Wv)) + r;
    dst = Wb + j;
  }
  const float4* s4 = (const float4*)src;
  float4 a = s4[0], b = s4[1];
  bf16x8 v;
  v[0] = (__bf16)a.x; v[1] = (__bf16)a.y; v[2] = (__bf16)a.z; v[3] = (__bf16)a.w;
  v[4] = (__bf16)b.x; v[5] = (__bf16)b.y; v[6] = (__bf16)b.z; v[7] = (__bf16)b.w;
  *(bf16x8*)dst = v;
}

// ---------------------------------------------------------------- QKV GEMM
// UNCHANGED r17/r20 config (best measured): 256x128 tile, 8 waves (4m x 2n),
// BK=64, 12 rounds, T14 reg-staged 2-barrier skeleton, grid 432, bf16 Xb.
// Q from full Xb; K/V gather compacted rows via idx[] on the fly.
// 128B LDS rows + 8-chunk XOR swizzle slot = c ^ (r&7).
// Q pre-scaled by 0.125*log2(e) for log2-domain softmax.
__global__ __launch_bounds__(512) void qkv_kernel(
    const __bf16* __restrict__ Xb, const int* __restrict__ idx,
    const int* __restrict__ counts, const __bf16* __restrict__ Wb,
    const float* __restrict__ bq, const float* __restrict__ bk,
    const float* __restrict__ bv,
    __bf16* __restrict__ Qb, __bf16* __restrict__ Kc,
    __bf16* __restrict__ Vtc) {
  __shared__ alignas(16) __bf16 As[16384];  // [256 rows][64 k]
  __shared__ alignas(16) __bf16 Bs[8192];   // [128 n-rows][64 k]
  int tid = threadIdx.x, lane = tid & 63, wid = tid >> 6;  // wid 0..7
  // grid 432: [0,192) Q (32 m-tiles x 6 n), [192,312) K (20 x 6), [312,432) V
  int bidx = blockIdx.x;
  int w, tm, n0;
  if (bidx < 192)      { w = 0; tm = bidx / 6;          n0 = (bidx % 6) * 128; }
  else if (bidx < 312) { w = 1; tm = (bidx - 192) / 6;  n0 = ((bidx - 192) % 6) * 128; }
  else                 { w = 2; tm = (bidx - 312) / 6;  n0 = ((bidx - 312) % 6) * 128; }
  int m0 = tm * 256;
  int wm = wid >> 1, wn = wid & 1;   // wm 0..3 (m), wn 0..1 (n)
  int la = lane & 15, lg = lane >> 4;

  // staging: r0 = tid>>3 (0..63), cs = tid&7; A pass p covers rows p*64+r0
  // (p=0..3), B pass p covers rows p*64+r0 (p=0..1).
  int r0 = tid >> 3, csw = (tid & 7) ^ (r0 & 7);
  long aoff[4];
  if (w == 0) {
#pragma unroll
    for (int p = 0; p < 4; p++)
      aoff[p] = (long)(m0 + p * 64 + r0) * HID + csw * 8;
  } else {
    // on-the-fly gather: compact row j -> original row idx[bI][j]
    int bI = m0 / NC, jbase = m0 - bI * NC;   // tiles never cross a batch
    int cnt = counts[bI];
#pragma unroll
    for (int p = 0; p < 4; p++) {
      int j = jbase + p * 64 + r0;
      int src = (j < cnt) ? idx[bI * SEQ + j] : 0;
      aoff[p] = (long)(bI * SEQ + src) * HID + csw * 8;
    }
  }
  long wbase = (long)w * HID * HID;
  long boff[2];
#pragma unroll
  for (int p = 0; p < 2; p++)
    boff[p] = wbase + (long)(n0 + p * 64 + r0) * HID + csw * 8;

  // fragment read offsets (element units): row r, k-chunk kk*4+lg
  int aoffL[2][4], boffL[2][4];
#pragma unroll
  for (int kk = 0; kk < 2; kk++)
#pragma unroll
    for (int i = 0; i < 4; i++) {
      int r = wm * 64 + i * 16 + la;          // 0..255
      aoffL[kk][i] = r * 64 + (((kk * 4 + lg) ^ (r & 7)) * 8);
      int rb = wn * 64 + i * 16 + la;         // 0..127
      boffL[kk][i] = rb * 64 + (((kk * 4 + lg) ^ (rb & 7)) * 8);
    }

  // prologue: load tile kt=0 into staging registers
  bf16x8 areg[4], breg[2];
#pragma unroll
  for (int p = 0; p < 4; p++) areg[p] = *(const bf16x8*)(Xb + aoff[p]);
#pragma unroll
  for (int p = 0; p < 2; p++) breg[p] = *(const bf16x8*)(Wb + boff[p]);

  f32x4 acc[4][4] = {};
  for (int kt = 0; kt < 12; kt++) {
    // write staged tile kt to LDS (vmcnt wait auto-inserted; loads had the
    // previous compute phase to land). WAR vs tile kt-1 readers: sync2 below.
#pragma unroll
    for (int p = 0; p < 4; p++)
      *(bf16x8*)(As + p * 4096 + tid * 8) = areg[p];
#pragma unroll
    for (int p = 0; p < 2; p++)
      *(bf16x8*)(Bs + p * 4096 + tid * 8) = breg[p];
    __syncthreads();  // sync1: tile kt visible to all waves

    // issue loads for tile kt+1 -> in flight under this tile's MFMAs
    // (kt=11 wraps to 0: harmless in-bounds re-load, never written)
    long kn = (kt + 1 == 12) ? 0 : (long)(kt + 1) * 64;
#pragma unroll
    for (int p = 0; p < 4; p++) areg[p] = *(const bf16x8*)(Xb + aoff[p] + kn);
#pragma unroll
    for (int p = 0; p < 2; p++) breg[p] = *(const bf16x8*)(Wb + boff[p] + kn);

#pragma unroll
    for (int kk = 0; kk < 2; kk++) {
      bf16x8 af[4], bfv[4];
#pragma unroll
      for (int i = 0; i < 4; i++) af[i] = *(const bf16x8*)(As + aoffL[kk][i]);
#pragma unroll
      for (int j = 0; j < 4; j++) bfv[j] = *(const bf16x8*)(Bs + boffL[kk][j]);
#pragma unroll
      for (int i = 0; i < 4; i++)
#pragma unroll
        for (int j = 0; j < 4; j++)
          acc[i][j] = MFMA(af[i], bfv[j], acc[i][j]);
    }
    __syncthreads();  // sync2: all waves done reading tile kt
  }

  // epilogue: bias add, bf16 convert.
  // w=0: Qb row-major (pre-scaled); w=1: Kc row-major [5120][768];
  // w=2: Vtc transposed [b][h][d][NC].
  const float* bias = (w == 0) ? bq : ((w == 1) ? bk : bv);
  const float qscale = (w == 0) ? 0.18033688011112042f : 1.0f;  // 0.125*log2e
#pragma unroll
  for (int j = 0; j < 4; j++) {
    int nc = n0 + wn * 64 + j * 16 + la;  // 0..767
    float bb = bias[nc];
#pragma unroll
    for (int i = 0; i < 4; i++) {
      int mrow0 = m0 + wm * 64 + i * 16 + lg * 4;
      f32x4 v = acc[i][j];
      if (w < 2) {
        __bf16* dst = (w == 0 ? Qb : Kc);
#pragma unroll
        for (int reg = 0; reg < 4; reg++)
          dst[(long)(mrow0 + reg) * HID + nc] = (__bf16)((v[reg] + bb) * qscale);
      } else {
        int bI = mrow0 / NC, j0 = mrow0 - bI * NC;  // tiles never cross NC
        int hh = nc >> 6, d = nc & 63;
        bf16x4 pv;
#pragma unroll
        for (int reg = 0; reg < 4; reg++) pv[reg] = (__bf16)(v[reg] + bb);
        *(bf16x4*)(Vtc + ((long)(bI * NH + hh) * HD + d) * NC + j0) = pv;
      }
    }
  }
}

// ---------------------------------------------------------------- attention
// r21: SWAPPED QK^T (MFMA(K,Q) -> S^T: lane = query la, keys in rows) with
// K rows staged in permutation nu(j) = (j>>5)*32 + ((j&15)>>2)*8 +
// ((j>>4)&1)*4 + (j&3) so the lane's 16 P-values ARE the PV A-fragment:
// P packs in-register, the Ps LDS round-trip (16 stores + 2 reads + lgkm
// chain) is GONE. acc/l layouts, V reads, rowsum-MFMA, epilogue unchanged;
// same key grouping and d-order in every MFMA -> bit-identical output.
// Scalar m_run/mx per lane (1 query/lane). Rescale (rare) reduces across
// lg-lanes (shfl 16/32) and fetches per-q corr via shfl. LDS 16KB.
// 8 waves/block = 128 q-rows (r19 lesson: keep >=6 waves/SIMD), grid 768.
__global__ __launch_bounds__(512) void attn_kernel(
    const __bf16* __restrict__ Qb, const __bf16* __restrict__ Kc,
    const __bf16* __restrict__ Vtc, const int* __restrict__ counts,
    float* __restrict__ out) {
  __shared__ alignas(16) __bf16 Ks[4096];  // [64 key-slots (permuted)][64 d]
  __shared__ alignas(16) __bf16 Vs[4096];  // [64 d][64 s (natural)]
  int tid = threadIdx.x, lane = tid & 63, wid = tid >> 6;  // wid 0..7
  int qt = blockIdx.x, h = blockIdx.y, b = blockIdx.z;
  int la = lane & 15, lg = lane >> 4;

  int cnt = counts[b];
  int ntiles = (cnt + 63) >> 6;   // >= 1 for this input (n_b ~ 1024)

  // Q fragments (used as B operand now; A/B frag layouts are symmetric so
  // the loads are unchanged: row = la, d = lg*8+i (+32))
  int qrow = qt * 128 + wid * 16 + la;
  const __bf16* qp = Qb + (long)(b * SEQ + qrow) * HID + h * HD + lg * 8;
  bf16x8 qa0 = *(const bf16x8*)qp;
  bf16x8 qa1 = *(const bf16x8*)(qp + 32);

  // staging maps (source pre-swizzled, LDS dest linear); 512 threads x 16B.
  // K: LDS slot r0 holds natural within-tile key nu(r0).
  int r0 = tid >> 3, cc = (tid & 7) ^ (r0 & 7);
  int nu = (r0 >> 5) * 32 + ((r0 & 15) >> 2) * 8 + ((r0 >> 4) & 1) * 4 + (r0 & 3);
  long kbase = (long)(b * NC + nu) * HID + h * HD + cc * 8;     // key rows
  long vbase = ((long)(b * NH + h) * HD + r0) * NC + cc * 8;    // d rows

  // fragment read offsets (row stride 64 elems = 128B, 8-chunk XOR).
  // K A-frag group g: row = g*16+la, d-chunk (half*4+lg)^(row&7).
  // V B-frag block jo: row(d) = jo*16+la, s-chunk (half*4+lg)^(row&7).
  int koffL[4][2];
#pragma unroll
  for (int j = 0; j < 4; j++) {
    int r = j * 16 + la;
    koffL[j][0] = r * 64 + (((0 + lg) ^ (r & 7)) * 8);
    koffL[j][1] = r * 64 + (((4 + lg) ^ (r & 7)) * 8);
  }

  float m_run = 0.f;                      // log2-domain running max (defer)
  float l_run[4] = {0.f, 0.f, 0.f, 0.f};  // q = lg*4+r layout (from MFMA D)
  f32x4 acc[4] = {};
  bf16x8 vone;
#pragma unroll
  for (int i = 0; i < 8; i++) vone[i] = (__bf16)1.0f;

  // prologue: load tile 0 into staging registers
  bf16x8 kreg = *(const bf16x8*)(Kc + kbase);
  bf16x8 vreg = *(const bf16x8*)(Vtc + vbase);

  for (int t = 0; t < ntiles; t++) {
    // write staged tile t to LDS (vmcnt wait auto-inserted; the loads had
    // the whole previous compute phase to land)
    *(bf16x8*)(Ks + tid * 8) = kreg;
    *(bf16x8*)(Vs + tid * 8) = vreg;
    __syncthreads();  // sync1: tile t visible to all waves

    // issue loads for tile t+1 -> in flight under this tile's compute
    // (last iteration wraps to tile 0: harmless in-bounds re-load)
    int tn = (t + 1 == ntiles) ? 0 : (t + 1);
    kreg = *(const bf16x8*)(Kc + kbase + (long)tn * (64 * HID));
    vreg = *(const bf16x8*)(Vtc + vbase + tn * 64);

    // S^T = K Q  (swapped: A = K-frag group g, B = Q). D: lane holds
    // query = la, key-slot rows lg*4+r of group g -> natural key
    // (g>>1)*32 + lg*8 + (g&1)*4 + r by the staging permutation.
    f32x4 s[4];
#pragma unroll
    for (int g = 0; g < 4; g++) {
      bf16x8 k0 = *(const bf16x8*)(Ks + koffL[g][0]);
      bf16x8 k1 = *(const bf16x8*)(Ks + koffL[g][1]);
      f32x4 z = {};
      z = MFMA(k0, qa0, z);
      z = MFMA(k1, qa1, z);
      s[g] = z;
    }

    // log2-domain arg; scalar per-lane max (one query per lane).
    float mx = -1e30f;
    if ((t + 1) * 64 <= cnt) {
      // fully-valid tile (16 of ~17): no mask compares at all
#pragma unroll
      for (int g = 0; g < 4; g++)
#pragma unroll
        for (int r = 0; r < 4; r++) {
          float a = s[g][r] - m_run;
          s[g][r] = a;
          mx = fmaxf(mx, a);
        }
    } else {
#pragma unroll
      for (int g = 0; g < 4; g++) {
        int kb = t * 64 + (g >> 1) * 32 + (g & 1) * 4 + lg * 8;
#pragma unroll
        for (int r = 0; r < 4; r++) {
          float mneg = ((kb + r) < cnt) ? 0.0f : -30000.0f;
          float a = s[g][r] + (mneg - m_run);
          s[g][r] = a;
          mx = fmaxf(mx, a);
        }
      }
    }
    if (__builtin_expect(!__all(mx <= 8.f), 0)) {
      // rare: true row-max for query la = reduce across lg-lanes
      float rm = fmaxf(mx, __shfl_xor(mx, 16));
      rm = fmaxf(rm, __shfl_xor(rm, 32));
      rm = fmaxf(rm, 0.0f);
      float corr = __builtin_amdgcn_exp2f(-rm);
      m_run += rm;
      // acc/l live in q = lg*4+r layout; corr for query q sits at lane q
      // (la = q, lg = 0; corr is uniform across lanes sharing la)
#pragma unroll
      for (int r = 0; r < 4; r++) {
        float cq = __shfl(corr, lg * 4 + r, 64);
        l_run[r] *= cq;
#pragma unroll
        for (int jo = 0; jo < 4; jo++) acc[jo][r] *= cq;
      }
#pragma unroll
      for (int g = 0; g < 4; g++)
#pragma unroll
        for (int r = 0; r < 4; r++) s[g][r] -= rm;
    }

    // P = exp2(arg) -> bf16, packed IN-REGISTER into PV A-fragments
    // (keys natural order by construction: pa0 = keys 0..31, pa1 = 32..63)
    bf16x8 pa0, pa1;
#pragma unroll
    for (int r = 0; r < 4; r++) {
      pa0[r]     = (__bf16)__builtin_amdgcn_exp2f(s[0][r]);
      pa0[4 + r] = (__bf16)__builtin_amdgcn_exp2f(s[1][r]);
      pa1[r]     = (__bf16)__builtin_amdgcn_exp2f(s[2][r]);
      pa1[4 + r] = (__bf16)__builtin_amdgcn_exp2f(s[3][r]);
    }

    // l += rowsum(P) via MFMA with ones-B (D rows = q = lg*4+r)
    f32x4 z = {};
    z = MFMA(pa0, vone, z);
    z = MFMA(pa1, vone, z);
#pragma unroll
    for (int r = 0; r < 4; r++) l_run[r] += z[r];

    // O += P V   (B-frag from Vs rows: row(d) = jo*16+la, s natural)
#pragma unroll
    for (int jo = 0; jo < 4; jo++) {
      bf16x8 v0 = *(const bf16x8*)(Vs + koffL[jo][0]);
      bf16x8 v1 = *(const bf16x8*)(Vs + koffL[jo][1]);
      acc[jo] = MFMA(pa0, v0, acc[jo]);
      acc[jo] = MFMA(pa1, v1, acc[jo]);
    }

    __syncthreads();  // sync2: all waves done reading tile t
  }

  // epilogue: out[b, s, h*64+d] = acc / l   (layout unchanged from r17)
#pragma unroll
  for (int jo = 0; jo < 4; jo++)
#pragma unroll
    for (int r = 0; r < 4; r++) {
      int row = qt * 128 + wid * 16 + lg * 4 + r;
      int d = jo * 16 + la;
      out[(long)(b * SEQ + row) * HID + h * HD + d] = acc[jo][r] / l_run[r];
    }
}

// ---------------------------------------------------------------- launch
extern "C" void kernel_launch(void* const* d_in, const int* in_sizes, int n_in,
                              void* d_out, int out_size, void* d_ws, size_t ws_size,
                              hipStream_t stream) {
  const float* X    = (const float*)d_in[0];
  const float* mask = (const float*)d_in[1];
  const float* Wq   = (const float*)d_in[2];
  const float* bq   = (const float*)d_in[3];
  const float* Wk   = (const float*)d_in[4];
  const float* bk   = (const float*)d_in[5];
  const float* Wv   = (const float*)d_in[6];
  const float* bv   = (const float*)d_in[7];

  __bf16* Xb  = (__bf16*)d_ws;           // 6291456
  __bf16* Wb  = Xb + 6291456;            // 1769472 (Wq,Wk,Wv)
  __bf16* Qb  = Wb + 1769472;            // 6291456
  __bf16* Kc  = Qb + 6291456;            // 3932160
  __bf16* Vtc = Kc + 3932160;            // 3932160, layout [b][h][d][NC]
  int* idx    = (int*)(Vtc + 3932160);   // 4*2048 ints
  int* counts = idx + NB * SEQ;          // 4 ints
  float* out  = (float*)d_out;

  prep_kernel<<<dim3(3940), dim3(256), 0, stream>>>(mask, X, Wq, Wk, Wv,
                                                    idx, counts, Xb, Wb);
  qkv_kernel<<<dim3(432), dim3(512), 0, stream>>>(Xb, idx, counts, Wb,
                                                  bq, bk, bv, Qb, Kc, Vtc);
  attn_kernel<<<dim3(16, 12, 4), dim3(512), 0, stream>>>(Qb, Kc, Vtc, counts,
                                                         out);
}